// Round 13
// baseline (215.149 us; speedup 1.0000x reference)
//
#include <hip/hip_runtime.h>
#include <hip/hip_bf16.h>

typedef __attribute__((ext_vector_type(8))) short short8;
typedef __attribute__((ext_vector_type(4))) float f32x4;
typedef __attribute__((ext_vector_type(4))) unsigned int u32x4;
typedef unsigned long long u64;
typedef unsigned short u16;
typedef unsigned int u32;

#define NODES 512
#define HIDDEN 512
#define NEDGES 16384

// qkv fragment regions (u16 offsets)
#define KOFF ((size_t)384 * 32 * 2 * 512)          // 12582912
#define VOFF ((size_t)2 * 384 * 32 * 2 * 512)      // 25165824

// ---- helpers ----
static __device__ __forceinline__ u16 f2bf(float f) {
  unsigned u = __float_as_uint(f);
  u += 0x7FFFu + ((u >> 16) & 1u);
  return (u16)(u >> 16);
}

static __device__ __forceinline__ void gld_lds16(const void* g, void* l) {
  __builtin_amdgcn_global_load_lds(
      (const __attribute__((address_space(1))) unsigned int*)g,
      (__attribute__((address_space(3))) unsigned int*)l, 16, 0, 0);
}

// ---- kernel 1: fused cast. x -> xb (linear bf16). W -> B-FRAGMENT layout:
// granule (z, ns=col>>4, kblk=k>>5): lane(l,j) holds W[ns*16+l][kblk*32+j*8+e]
__global__ void cast_all(const float* __restrict__ x, const float* __restrict__ wq,
                         const float* __restrict__ wk, const float* __restrict__ wv,
                         u16* __restrict__ xb, u16* __restrict__ wb) {
  const int n4 = 3145728 + 196608;
  int stride = gridDim.x * blockDim.x;
  for (int i = blockIdx.x * blockDim.x + threadIdx.x; i < n4; i += stride) {
    if (i < 3145728) {
      float4 v = reinterpret_cast<const float4*>(x)[i];
      ushort4 o;
      o.x = f2bf(v.x); o.y = f2bf(v.y); o.z = f2bf(v.z); o.w = f2bf(v.w);
      reinterpret_cast<ushort4*>(xb)[i] = o;
    } else {
      int t = i - 3145728;
      int z = t >> 16;
      int wl = t & 65535;
      int jrow = wl >> 7;      // W row = output column
      int k = (wl & 127) * 4;  // k%8 in {0,4}
      const float* src = (z == 0) ? wq : (z == 1) ? wk : wv;
      float4 v = reinterpret_cast<const float4*>(src)[wl];
      ushort4 o;
      o.x = f2bf(v.x); o.y = f2bf(v.y); o.z = f2bf(v.z); o.w = f2bf(v.w);
      size_t didx = (((size_t)(z * 32 + (jrow >> 4)) * 16 + (k >> 5)) * 64
                     + (((k >> 3) & 3) * 16 + (jrow & 15))) * 8 + (k & 7);
      *reinterpret_cast<ushort4*>(wb + didx) = o;
    }
  }
}

// ---- kernel 2: adjacency bitmask scatter ----
__global__ void mask_scatter(const int* __restrict__ e, u64* __restrict__ bits) {
  int i = blockIdx.x * blockDim.x + threadIdx.x;
  if (i < NEDGES) {
    int src = e[i];
    int dst = e[NEDGES + i];
    atomicOr(&bits[src * 8 + (dst >> 6)], 1ull << (dst & 63));
  }
}

// ---- kernel 2b: expand mask bits to AND-words in PV A-frag layout ----
__global__ void mask_frag(const u64* __restrict__ bits, u32* __restrict__ mf) {
  int idx = blockIdx.x * 256 + threadIdx.x;   // 0..131071
  int w = idx & 3;
  int lane = (idx >> 2) & 63;
  int hh = (idx >> 8) & 1;
  int kt = (idx >> 9) & 7;
  int qsg = idx >> 12;
  int q = qsg * 16 + (lane & 15);
  int bit = hh * 32 + (lane >> 4) * 8 + 2 * w;
  u64 row = bits[q * 8 + kt];
  u32 b0 = (u32)(row >> bit) & 1u;
  u32 b1 = (u32)(row >> (bit + 1)) & 1u;
  mf[idx] = (b0 ? 0xFFFFu : 0u) | (b1 ? 0xFFFF0000u : 0u);
}

// ---- kernel 3: QKV GEMM — PERSISTENT 3-m-tile blocks (grid 768) ----
// Round-11 body (B frag-direct from L2, 32KB LDS, counted vmcnt, T2
// swizzle) + each block owns 3 consecutive m-tiles for its fixed (n0,z):
// exactly 3 blocks/CU co-resident, ONE scheduling generation, zero tail
// (rounds 9/11 paid 2.25+ generations). Prologue/epilogue amortized 3x.
// Tile-boundary uses a full vmcnt(0) drain — epilogue STORES share vmcnt
// on gfx9-lineage, so counted arithmetic must not straddle the epilogue.
// (256,2) kept — (256,4) forced VGPR=64 and spilled acc (round 5).
__global__ __launch_bounds__(256, 2)
void qkv_gemm(const u16* __restrict__ xb, const u16* __restrict__ wfrag,
              const float* __restrict__ bq, const float* __restrict__ bk,
              const float* __restrict__ bv, u16* __restrict__ qkv) {
  __shared__ u16 As[2][128 * 64];   // 2 x 16KB (A only; B never in LDS)

  const int blk = blockIdx.x;
  const int xcd = blk & 7;
  const int i = blk >> 3;            // 0..95
  const int g = i / 12;              // m-group 0..7
  const int r12 = i % 12;            // (n0,z) fastest: A-panel sharers adjacent
  const int z = r12 >> 2;
  const int n0 = (r12 & 3) * 128;

  const float* bias = (z == 0) ? bq : (z == 1) ? bk : bv;

  const int tid = threadIdx.x;
  const int lane = tid & 63;
  const int w = tid >> 6;
  const int wr = w >> 1, wc = w & 1;
  const int l = lane & 15, j = lane >> 4;
  const int sl = l & 7;                           // row&7 for swizzled reads
  const int kb = ((lane & 7) ^ (lane >> 3)) * 16; // pre-swizzled source col

  // B-frag base for this wave's column panel (L2-hot, 1.5MB total)
  const u16* wf = wfrag + (((size_t)z * 32 + (n0 >> 4) + wc * 4) * 16) * 512 + lane * 8;

#define STAGE_A(bb, mm, kt_) do {                                               \
    const int k0_ = (kt_) * 64;                                                 \
    _Pragma("unroll")                                                           \
    for (int t_ = 0; t_ < 4; ++t_) {                                            \
      int c_ = w * 4 + t_;                                                      \
      int row_ = c_ * 8 + (lane >> 3);                                          \
      gld_lds16((const char*)xb + ((size_t)((mm) + row_) * 512 + k0_) * 2 + kb, \
                (char*)&As[bb][0] + c_ * 1024);                                 \
    }                                                                           \
  } while (0)

#pragma unroll 1
  for (int tt = 0; tt < 3; ++tt) {
    const int m0 = (xcd * 24 + g * 3 + tt) * 128;

    f32x4 acc[4][4] = {};

    // tile prologue: full drain (also retires prev tile's epilogue stores)
    STAGE_A(0, m0, 0);
    asm volatile("s_waitcnt vmcnt(0)" ::: "memory");
    __builtin_amdgcn_s_barrier();
    int cur = 0;

    for (int kt = 0; kt < 8; ++kt) {
      // B fragments for THIS kt — issued first (oldest) so the compiler's
      // wait for them never drains the A prefetch below.
      short8 bf[4][2];
#pragma unroll
      for (int ni = 0; ni < 4; ++ni)
#pragma unroll
        for (int kk = 0; kk < 2; ++kk)
          bf[ni][kk] = *(const short8*)(wf + ((ni * 16) + (kt * 2 + kk)) * 512);

      if (kt < 7) {
        STAGE_A(cur ^ 1, m0, kt + 1);   // next A tile in flight
        // outstanding: stageA(kt)[4 oldest] + B(kt)[8] + stageA(kt+1)[4]
        asm volatile("s_waitcnt vmcnt(12)" ::: "memory");  // stageA(kt) done
      } else {
        // outstanding: stageA(7)[4 oldest] + B(7)[8]
        asm volatile("s_waitcnt vmcnt(8)" ::: "memory");
      }
      __builtin_amdgcn_s_barrier();     // collective: As[cur] fully written

#pragma unroll
      for (int kk = 0; kk < 2; ++kk) {
        short8 a[4];
#pragma unroll
        for (int mi = 0; mi < 4; ++mi)
          a[mi] = *(const short8*)(&As[cur][0] + (wr * 64 + mi * 16 + l) * 64 +
                                   (((kk * 4 + j) ^ sl) * 8));
        if (z == 2) {
#pragma unroll
          for (int mi = 0; mi < 4; ++mi)
#pragma unroll
            for (int ni = 0; ni < 4; ++ni)
              acc[mi][ni] = __builtin_amdgcn_mfma_f32_16x16x32_bf16(a[mi], bf[ni][kk], acc[mi][ni], 0, 0, 0);
        } else {
#pragma unroll
          for (int mi = 0; mi < 4; ++mi)
#pragma unroll
            for (int ni = 0; ni < 4; ++ni)
              acc[mi][ni] = __builtin_amdgcn_mfma_f32_16x16x32_bf16(bf[ni][kk], a[mi], acc[mi][ni], 0, 0, 0);
        }
      }

      if (kt < 7) {
        // As[cur] reads done before any wave's next STAGE overwrites it;
        // no vmcnt — the A prefetch stays in flight.
        asm volatile("s_waitcnt lgkmcnt(0)" ::: "memory");
        __builtin_amdgcn_s_barrier();
      }
      cur ^= 1;
    }

    // ---- epilogue for this m-tile ----
    const int bs = m0 >> 9;
    const int hh = (n0 >> 6) + wc;
    const int bh = bs * 8 + hh;

    if (z == 2) {
      // unswapped: col l -> d (dd = ni*16+l), rows j*4+r -> key
      const int ktb = ((m0 & 511) >> 6) + wr;
#pragma unroll
      for (int ni = 0; ni < 4; ++ni) {
        int jcol = n0 + wc * 64 + ni * 16 + l;
        float bv_ = bias[jcol];
        int ds = ni;
#pragma unroll
        for (int mi = 0; mi < 4; ++mi) {
          int kk2 = mi >> 1, oct = ((mi & 1) << 1) | (j >> 1);
          ushort4 pk;
#pragma unroll
          for (int r = 0; r < 4; ++r) pk[r] = f2bf(acc[mi][ni][r] + bv_);
          size_t idx = VOFF + (((((size_t)bh * 8 + ktb) * 2 + kk2) * 4 + ds) * 512)
                     + (oct * 16 + l) * 8 + (j & 1) * 4;
          *reinterpret_cast<ushort4*>(qkv + idx) = pk;
        }
      }
    } else {
      // swapped: rows j*4+r -> d (dd = ni*16+j*4+r), col l -> node
#pragma unroll
      for (int ni = 0; ni < 4; ++ni) {
        int n_base = n0 + wc * 64 + ni * 16 + j * 4;
        float4 b4 = *reinterpret_cast<const float4*>(bias + n_base);
        int kk = ni >> 1, oct = ((ni & 1) << 1) | (j >> 1);
#pragma unroll
        for (int mi = 0; mi < 4; ++mi) {
          ushort4 pk;
#pragma unroll
          for (int r = 0; r < 4; ++r) pk[r] = f2bf(acc[mi][ni][r] + (&b4.x)[r]);
          size_t idx;
          if (z == 0) {
            int qsg = ((m0 & 511) >> 4) + wr * 4 + mi;
            idx = ((((size_t)bh * 32 + qsg) * 2 + kk) * 512) + (oct * 16 + l) * 8 + (j & 1) * 4;
          } else {
            int ktb = ((m0 & 511) >> 6) + wr;
            idx = KOFF + (((((size_t)bh * 8 + ktb) * 4 + mi) * 2 + kk) * 512)
                + (oct * 16 + l) * 8 + (j & 1) * 4;
          }
          *reinterpret_cast<ushort4*>(qkv + idx) = pk;
        }
      }
    }
  }
#undef STAGE_A
}

// ---- kernel 4: masked attention — fragment-direct, no LDS, no barriers ----
__global__ __launch_bounds__(256, 2)
void attn_kernel(const u16* __restrict__ qkv, const u32* __restrict__ mf,
                 float* __restrict__ out) {
  const int blk = blockIdx.x;
  const int xcd = blk & 7;
  const int i = blk >> 3;                 // 0..191
  const int bh = xcd * 48 + (i >> 2);
  const int qq = i & 3;
  const int bs = bh >> 3, h = bh & 7;
  const int tid = threadIdx.x;
  const int lane = tid & 63;
  const int w = tid >> 6;
  const int l = lane & 15, j = lane >> 4;
  const int qb = qq * 8 + w * 2;          // qsg base (2 subtiles per wave)

  // Q fragments, held all kernel
  short8 qf[2][2];
#pragma unroll
  for (int qs = 0; qs < 2; ++qs)
#pragma unroll
    for (int kk = 0; kk < 2; ++kk)
      qf[qs][kk] = *(const short8*)(qkv + (((size_t)bh * 32 + qb + qs) * 2 + kk) * 512 + lane * 8);

  // phase-walking pointers (strength-reduced; frag offsets are immediates)
  const u16* Kp = qkv + KOFF + (size_t)bh * 32768 + lane * 8;
  const u16* Vp = qkv + VOFF + (size_t)bh * 32768 + lane * 8;
  const u32* M0 = mf + (qb + 0) * 4096 + lane * 4;
  const u32* M1 = mf + (qb + 1) * 4096 + lane * 4;

  f32x4 o[2][4] = {};
  f32x4 osum[2] = {};
  short8 ones;
#pragma unroll
  for (int t = 0; t < 8; ++t) ones[t] = (short)0x3F80;  // bf16 1.0

#pragma unroll 1
  for (int p = 0; p < 16; ++p) {
    // K fragments (2 ks-subtiles x 2 kk) and V fragments (4 d-subtiles)
    short8 kf2[2][2];
#pragma unroll
    for (int lks = 0; lks < 2; ++lks)
#pragma unroll
      for (int kk = 0; kk < 2; ++kk)
        kf2[lks][kk] = *(const short8*)(Kp + (lks * 2 + kk) * 512);
    short8 vf[4];
#pragma unroll
    for (int ds = 0; ds < 4; ++ds)
      vf[ds] = *(const short8*)(Vp + ds * 512);
    u32x4 am0 = *reinterpret_cast<const u32x4*>(M0);
    u32x4 am1 = *reinterpret_cast<const u32x4*>(M1);

#pragma unroll
    for (int qs = 0; qs < 2; ++qs) {
      // QK^T: col l = q, row j*4+r = key-in-16 of subtile lks
      f32x4 st[2] = {};
#pragma unroll
      for (int lks = 0; lks < 2; ++lks)
#pragma unroll
        for (int kk = 0; kk < 2; ++kk)
          st[lks] = __builtin_amdgcn_mfma_f32_16x16x32_bf16(
              kf2[lks][kk], qf[qs][kk], st[lks], 0, 0, 0);

      // P = exp2(s*log2e/8) (unmasked; scores bounded), pack to bf16
      float pr[8];
#pragma unroll
      for (int lks = 0; lks < 2; ++lks)
#pragma unroll
        for (int r = 0; r < 4; ++r)
          pr[lks * 4 + r] = __builtin_exp2f(st[lks][r] * 0.18033688f);
      u32 X0, X1, Y0, Y1;
      asm("v_cvt_pk_bf16_f32 %0, %1, %2" : "=v"(X0) : "v"(pr[0]), "v"(pr[1]));
      asm("v_cvt_pk_bf16_f32 %0, %1, %2" : "=v"(X1) : "v"(pr[2]), "v"(pr[3]));
      asm("v_cvt_pk_bf16_f32 %0, %1, %2" : "=v"(Y0) : "v"(pr[4]), "v"(pr[5]));
      asm("v_cvt_pk_bf16_f32 %0, %1, %2" : "=v"(Y1) : "v"(pr[6]), "v"(pr[7]));
      asm("v_permlane32_swap_b32 %0, %1" : "+v"(X0), "+v"(Y0));
      asm("v_permlane32_swap_b32 %0, %1" : "+v"(X1), "+v"(Y1));
      asm("v_permlane16_swap_b32 %0, %1" : "+v"(X0), "+v"(Y0));
      asm("v_permlane16_swap_b32 %0, %1" : "+v"(X1), "+v"(Y1));
      // mask: AND in the A-frag layout (zeroes masked-out keys exactly)
      const u32x4 am = qs ? am1 : am0;
      u32x4 paw;
      paw[0] = X0 & am[0];
      paw[1] = X1 & am[1];
      paw[2] = Y0 & am[2];
      paw[3] = Y1 & am[3];
      short8 pa = __builtin_bit_cast(short8, paw);
      // row-sum on the MFMA pipe (same C layout as o)
      osum[qs] = __builtin_amdgcn_mfma_f32_16x16x32_bf16(pa, ones, osum[qs], 0, 0, 0);
#pragma unroll
      for (int ds = 0; ds < 4; ++ds)
        o[qs][ds] = __builtin_amdgcn_mfma_f32_16x16x32_bf16(pa, vf[ds], o[qs][ds], 0, 0, 0);
    }

    Kp += 2048; Vp += 2048; M0 += 256; M1 += 256;
  }

  // epilogue: normalize (osum already in o's lane layout) and store
#pragma unroll
  for (int qs = 0; qs < 2; ++qs) {
    f32x4 inv4;
#pragma unroll
    for (int r = 0; r < 4; ++r) inv4[r] = 1.0f / osum[qs][r];
#pragma unroll
    for (int ds = 0; ds < 4; ++ds) {
      int d = ds * 16 + l;
#pragma unroll
      for (int r = 0; r < 4; ++r) {
        int node = (qb + qs) * 16 + j * 4 + r;
        out[(size_t)bs * 262144 + (size_t)node * 512 + h * 64 + d] = o[qs][ds][r] * inv4[r];
      }
    }
  }
}

// ---- launcher ----
extern "C" void kernel_launch(void* const* d_in, const int* in_sizes, int n_in,
                              void* d_out, int out_size, void* d_ws, size_t ws_size,
                              hipStream_t stream) {
  const float* x  = (const float*)d_in[0];
  const int*   e  = (const int*)d_in[1];
  const float* Wq = (const float*)d_in[2];
  const float* bq = (const float*)d_in[3];
  const float* Wk = (const float*)d_in[4];
  const float* bk = (const float*)d_in[5];
  const float* Wv = (const float*)d_in[6];
  const float* bv = (const float*)d_in[7];
  float* out = (float*)d_out;

  char* ws = (char*)d_ws;
  u16* xb   = (u16*)(ws);                 // 24576*512 bf16 = 25165824 B
  u16* wb   = (u16*)(ws + 25165824);      // 3*512*512 bf16 = 1572864 B (frag layout)
  u16* qkv  = (u16*)(ws + 26738688);      // 3*384*512*64 bf16 = 75497472 B
  u64* mb   = (u64*)(ws + 102236160);     // 512*8 u64 = 32768 B
  u32* mfr  = (u32*)(ws + 102268928);     // 131072 u32 = 524288 B

  hipMemsetAsync(mb, 0, 512 * 8 * sizeof(u64), stream);
  mask_scatter<<<(NEDGES + 255) / 256, 256, 0, stream>>>(e, mb);
  mask_frag<<<512, 256, 0, stream>>>(mb, mfr);

  cast_all<<<2048, 256, 0, stream>>>(x, Wq, Wk, Wv, xb, wb);

  qkv_gemm<<<768, 256, 0, stream>>>(xb, wb, bq, bk, bv, qkv);
  attn_kernel<<<1536, 256, 0, stream>>>(qkv, mfr, out);
}

// Round 14
// 120.390 us; speedup vs baseline: 1.7871x; 1.7871x over previous
//
#include <hip/hip_runtime.h>
#include <hip/hip_bf16.h>

typedef __attribute__((ext_vector_type(8))) short short8;
typedef __attribute__((ext_vector_type(4))) float f32x4;
typedef __attribute__((ext_vector_type(4))) unsigned int u32x4;
typedef unsigned long long u64;
typedef unsigned short u16;
typedef unsigned int u32;

#define NODES 512
#define HIDDEN 512
#define NEDGES 16384

// qkv fragment regions (u16 offsets)
#define KOFF ((size_t)384 * 32 * 2 * 512)          // 12582912
#define VOFF ((size_t)2 * 384 * 32 * 2 * 512)      // 25165824

// ---- helpers ----
static __device__ __forceinline__ u16 f2bf(float f) {
  unsigned u = __float_as_uint(f);
  u += 0x7FFFu + ((u >> 16) & 1u);
  return (u16)(u >> 16);
}

static __device__ __forceinline__ void gld_lds16(const void* g, void* l) {
  __builtin_amdgcn_global_load_lds(
      (const __attribute__((address_space(1))) unsigned int*)g,
      (__attribute__((address_space(3))) unsigned int*)l, 16, 0, 0);
}

// ---- kernel 1: fused fp32 -> bf16 cast of x and the 3 weight matrices ----
__global__ void cast_all(const float* __restrict__ x, const float* __restrict__ wq,
                         const float* __restrict__ wk, const float* __restrict__ wv,
                         u16* __restrict__ xb, u16* __restrict__ wb) {
  const int n4 = 3145728 + 196608;
  int stride = gridDim.x * blockDim.x;
  for (int i = blockIdx.x * blockDim.x + threadIdx.x; i < n4; i += stride) {
    float4 v;
    u16* dst;
    int di;
    if (i < 3145728) {
      v = reinterpret_cast<const float4*>(x)[i];
      dst = xb; di = i;
    } else {
      int t = i - 3145728;
      const float* src = (t < 65536) ? wq : (t < 131072) ? wk : wv;
      v = reinterpret_cast<const float4*>(src)[t & 65535];
      dst = wb; di = t;
    }
    ushort4 o;
    o.x = f2bf(v.x); o.y = f2bf(v.y); o.z = f2bf(v.z); o.w = f2bf(v.w);
    reinterpret_cast<ushort4*>(dst)[di] = o;
  }
}

// ---- kernel 2: edges -> AND-word mask fragments DIRECTLY (one atomicOr
// per edge), replacing the mask_scatter -> u64-bitmask -> mask_frag chain.
// mf[qsg][kt][hh][lane][w]: edge (q,key) sets halfword (key&1) of word
// (key>>1)&3 at lane ((key>>3)&3)*16 + (q&15). Requires mf pre-zeroed.
__global__ void edge_mf(const int* __restrict__ e, u32* __restrict__ mf) {
  int i = blockIdx.x * 256 + threadIdx.x;
  if (i < NEDGES) {
    int q = e[i];
    int key = e[NEDGES + i];
    int lane = ((key >> 3) & 3) * 16 + (q & 15);
    int idx = (((q >> 4) * 8 + (key >> 6)) * 2 + ((key >> 5) & 1)) * 256
            + lane * 4 + ((key >> 1) & 3);
    atomicOr(&mf[idx], 0xFFFFu << ((key & 1) * 16));
  }
}

// ---- kernel 3: fused QKV GEMM — round-9 double-buffer + counted vmcnt ----
// BEST-KNOWN GEMM (57.7us): A+B staged via global_load_lds into 2x32KB LDS,
// raw s_barrier + s_waitcnt vmcnt(8) (prefetch stays in flight across the
// barrier), T2 both-sides XOR swizzle (conflicts 0).
// NEW vs round 9: nz-fastest block order — all 12 (n0,z) blocks per
// A-panel are consecutive/co-resident (round 12 proved FETCH 68->47MB).
// Frozen: (256,2) [(256,4) spilled, round 5]; no persistent loop [spilled,
// round 13]; no reg-staged cast [T14 cost, round 12].
__global__ __launch_bounds__(256, 2)
void qkv_gemm(const u16* __restrict__ xb, const u16* __restrict__ wb,
              const float* __restrict__ bq, const float* __restrict__ bk,
              const float* __restrict__ bv, u16* __restrict__ qkv) {
  __shared__ u16 As[2][128 * 64];
  __shared__ u16 Bs[2][128 * 64];

  const int blk = blockIdx.x;
  const int xcd = blk & 7;
  const int i = blk >> 3;            // 0..287
  const int m0 = (xcd * 24 + i / 12) * 128;
  const int r12 = i % 12;            // nz fastest: A-panel sharers adjacent
  const int z = r12 >> 2;
  const int n0 = (r12 & 3) * 128;

  const u16* Wz = wb + (size_t)z * (512 * 512);
  const float* bias = (z == 0) ? bq : (z == 1) ? bk : bv;

  const int tid = threadIdx.x;
  const int lane = tid & 63;
  const int w = tid >> 6;
  const int wr = w >> 1, wc = w & 1;
  const int l = lane & 15, j = lane >> 4;
  const int sl = l & 7;                           // row&7 for swizzled reads
  const int kb = ((lane & 7) ^ (lane >> 3)) * 16; // pre-swizzled source col

#define STAGE(bb, kt_) do {                                                     \
    const int k0_ = (kt_) * 64;                                                 \
    _Pragma("unroll")                                                           \
    for (int t_ = 0; t_ < 4; ++t_) {                                            \
      int c_ = w * 4 + t_;                                                      \
      int row_ = c_ * 8 + (lane >> 3);                                          \
      gld_lds16((const char*)xb + ((size_t)(m0 + row_) * 512 + k0_) * 2 + kb,   \
                (char*)&As[bb][0] + c_ * 1024);                                 \
      gld_lds16((const char*)Wz + ((size_t)(n0 + row_) * 512 + k0_) * 2 + kb,   \
                (char*)&Bs[bb][0] + c_ * 1024);                                 \
    }                                                                           \
  } while (0)

  f32x4 acc[4][4] = {};

  STAGE(0, 0);
  int cur = 0;

  for (int kt = 0; kt < 8; ++kt) {
    if (kt < 7) {
      STAGE(cur ^ 1, kt + 1);   // 8 more loads in flight (next tile)
      asm volatile("s_waitcnt vmcnt(8)" ::: "memory");  // own buf[cur] loads done
    } else {
      asm volatile("s_waitcnt vmcnt(0)" ::: "memory");  // last tile: full drain
    }
    __builtin_amdgcn_s_barrier();   // collective: buf[cur] fully written

#pragma unroll
    for (int kk = 0; kk < 2; ++kk) {
      short8 a[4], b[4];
#pragma unroll
      for (int mi = 0; mi < 4; ++mi)
        a[mi] = *(const short8*)(&As[cur][0] + (wr * 64 + mi * 16 + l) * 64 +
                                 (((kk * 4 + j) ^ sl) * 8));
#pragma unroll
      for (int ni = 0; ni < 4; ++ni)
        b[ni] = *(const short8*)(&Bs[cur][0] + (wc * 64 + ni * 16 + l) * 64 +
                                 (((kk * 4 + j) ^ sl) * 8));
      if (z == 2) {
#pragma unroll
        for (int mi = 0; mi < 4; ++mi)
#pragma unroll
          for (int ni = 0; ni < 4; ++ni)
            acc[mi][ni] = __builtin_amdgcn_mfma_f32_16x16x32_bf16(a[mi], b[ni], acc[mi][ni], 0, 0, 0);
      } else {
#pragma unroll
        for (int mi = 0; mi < 4; ++mi)
#pragma unroll
          for (int ni = 0; ni < 4; ++ni)
            acc[mi][ni] = __builtin_amdgcn_mfma_f32_16x16x32_bf16(b[ni], a[mi], acc[mi][ni], 0, 0, 0);
      }
    }

    if (kt < 7) {
      // reads of buf[cur] done before any wave's next STAGE overwrites it;
      // no vmcnt here — the prefetch stays in flight.
      asm volatile("s_waitcnt lgkmcnt(0)" ::: "memory");
      __builtin_amdgcn_s_barrier();
    }
    cur ^= 1;
  }
#undef STAGE

  const int bs = m0 >> 9;
  const int hh = (n0 >> 6) + wc;
  const int bh = bs * 8 + hh;

  if (z == 2) {
    // unswapped: col l -> d (dd = ni*16+l), rows j*4+r -> key
    const int ktb = ((m0 & 511) >> 6) + wr;
#pragma unroll
    for (int ni = 0; ni < 4; ++ni) {
      int jcol = n0 + wc * 64 + ni * 16 + l;
      float bv_ = bias[jcol];
      int ds = ni;
#pragma unroll
      for (int mi = 0; mi < 4; ++mi) {
        int kk2 = mi >> 1, oct = ((mi & 1) << 1) | (j >> 1);
        ushort4 pk;
#pragma unroll
        for (int r = 0; r < 4; ++r) pk[r] = f2bf(acc[mi][ni][r] + bv_);
        size_t idx = VOFF + (((((size_t)bh * 8 + ktb) * 2 + kk2) * 4 + ds) * 512)
                   + (oct * 16 + l) * 8 + (j & 1) * 4;
        *reinterpret_cast<ushort4*>(qkv + idx) = pk;
      }
    }
  } else {
    // swapped: rows j*4+r -> d (dd = ni*16+j*4+r), col l -> node
#pragma unroll
    for (int ni = 0; ni < 4; ++ni) {
      int n_base = n0 + wc * 64 + ni * 16 + j * 4;
      float4 b4 = *reinterpret_cast<const float4*>(bias + n_base);
      int kk = ni >> 1, oct = ((ni & 1) << 1) | (j >> 1);
#pragma unroll
      for (int mi = 0; mi < 4; ++mi) {
        ushort4 pk;
#pragma unroll
        for (int r = 0; r < 4; ++r) pk[r] = f2bf(acc[mi][ni][r] + (&b4.x)[r]);
        size_t idx;
        if (z == 0) {
          int qsg = ((m0 & 511) >> 4) + wr * 4 + mi;
          idx = ((((size_t)bh * 32 + qsg) * 2 + kk) * 512) + (oct * 16 + l) * 8 + (j & 1) * 4;
        } else {
          int ktb = ((m0 & 511) >> 6) + wr;
          idx = KOFF + (((((size_t)bh * 8 + ktb) * 4 + mi) * 2 + kk) * 512)
              + (oct * 16 + l) * 8 + (j & 1) * 4;
        }
        *reinterpret_cast<ushort4*>(qkv + idx) = pk;
      }
    }
  }
}

// ---- kernel 4: masked attention — fragment-direct, no LDS, no barriers ----
__global__ __launch_bounds__(256, 2)
void attn_kernel(const u16* __restrict__ qkv, const u32* __restrict__ mf,
                 float* __restrict__ out) {
  const int blk = blockIdx.x;
  const int xcd = blk & 7;
  const int i = blk >> 3;                 // 0..191
  const int bh = xcd * 48 + (i >> 2);
  const int qq = i & 3;
  const int bs = bh >> 3, h = bh & 7;
  const int tid = threadIdx.x;
  const int lane = tid & 63;
  const int w = tid >> 6;
  const int l = lane & 15, j = lane >> 4;
  const int qb = qq * 8 + w * 2;          // qsg base (2 subtiles per wave)

  // Q fragments, held all kernel
  short8 qf[2][2];
#pragma unroll
  for (int qs = 0; qs < 2; ++qs)
#pragma unroll
    for (int kk = 0; kk < 2; ++kk)
      qf[qs][kk] = *(const short8*)(qkv + (((size_t)bh * 32 + qb + qs) * 2 + kk) * 512 + lane * 8);

  // phase-walking pointers (strength-reduced; frag offsets are immediates)
  const u16* Kp = qkv + KOFF + (size_t)bh * 32768 + lane * 8;
  const u16* Vp = qkv + VOFF + (size_t)bh * 32768 + lane * 8;
  const u32* M0 = mf + (qb + 0) * 4096 + lane * 4;
  const u32* M1 = mf + (qb + 1) * 4096 + lane * 4;

  f32x4 o[2][4] = {};
  f32x4 osum[2] = {};
  short8 ones;
#pragma unroll
  for (int t = 0; t < 8; ++t) ones[t] = (short)0x3F80;  // bf16 1.0

#pragma unroll 1
  for (int p = 0; p < 16; ++p) {
    // K fragments (2 ks-subtiles x 2 kk) and V fragments (4 d-subtiles)
    short8 kf2[2][2];
#pragma unroll
    for (int lks = 0; lks < 2; ++lks)
#pragma unroll
      for (int kk = 0; kk < 2; ++kk)
        kf2[lks][kk] = *(const short8*)(Kp + (lks * 2 + kk) * 512);
    short8 vf[4];
#pragma unroll
    for (int ds = 0; ds < 4; ++ds)
      vf[ds] = *(const short8*)(Vp + ds * 512);
    u32x4 am0 = *reinterpret_cast<const u32x4*>(M0);
    u32x4 am1 = *reinterpret_cast<const u32x4*>(M1);

#pragma unroll
    for (int qs = 0; qs < 2; ++qs) {
      // QK^T: col l = q, row j*4+r = key-in-16 of subtile lks
      f32x4 st[2] = {};
#pragma unroll
      for (int lks = 0; lks < 2; ++lks)
#pragma unroll
        for (int kk = 0; kk < 2; ++kk)
          st[lks] = __builtin_amdgcn_mfma_f32_16x16x32_bf16(
              kf2[lks][kk], qf[qs][kk], st[lks], 0, 0, 0);

      // P = exp2(s*log2e/8) (unmasked; scores bounded), pack to bf16
      float pr[8];
#pragma unroll
      for (int lks = 0; lks < 2; ++lks)
#pragma unroll
        for (int r = 0; r < 4; ++r)
          pr[lks * 4 + r] = __builtin_exp2f(st[lks][r] * 0.18033688f);
      u32 X0, X1, Y0, Y1;
      asm("v_cvt_pk_bf16_f32 %0, %1, %2" : "=v"(X0) : "v"(pr[0]), "v"(pr[1]));
      asm("v_cvt_pk_bf16_f32 %0, %1, %2" : "=v"(X1) : "v"(pr[2]), "v"(pr[3]));
      asm("v_cvt_pk_bf16_f32 %0, %1, %2" : "=v"(Y0) : "v"(pr[4]), "v"(pr[5]));
      asm("v_cvt_pk_bf16_f32 %0, %1, %2" : "=v"(Y1) : "v"(pr[6]), "v"(pr[7]));
      asm("v_permlane32_swap_b32 %0, %1" : "+v"(X0), "+v"(Y0));
      asm("v_permlane32_swap_b32 %0, %1" : "+v"(X1), "+v"(Y1));
      asm("v_permlane16_swap_b32 %0, %1" : "+v"(X0), "+v"(Y0));
      asm("v_permlane16_swap_b32 %0, %1" : "+v"(X1), "+v"(Y1));
      // mask: AND in the A-frag layout (zeroes masked-out keys exactly)
      const u32x4 am = qs ? am1 : am0;
      u32x4 paw;
      paw[0] = X0 & am[0];
      paw[1] = X1 & am[1];
      paw[2] = Y0 & am[2];
      paw[3] = Y1 & am[3];
      short8 pa = __builtin_bit_cast(short8, paw);
      // row-sum on the MFMA pipe (same C layout as o)
      osum[qs] = __builtin_amdgcn_mfma_f32_16x16x32_bf16(pa, ones, osum[qs], 0, 0, 0);
#pragma unroll
      for (int ds = 0; ds < 4; ++ds)
        o[qs][ds] = __builtin_amdgcn_mfma_f32_16x16x32_bf16(pa, vf[ds], o[qs][ds], 0, 0, 0);
    }

    Kp += 2048; Vp += 2048; M0 += 256; M1 += 256;
  }

  // epilogue: normalize (osum already in o's lane layout) and store
#pragma unroll
  for (int qs = 0; qs < 2; ++qs) {
    f32x4 inv4;
#pragma unroll
    for (int r = 0; r < 4; ++r) inv4[r] = 1.0f / osum[qs][r];
#pragma unroll
    for (int ds = 0; ds < 4; ++ds) {
      int d = ds * 16 + l;
#pragma unroll
      for (int r = 0; r < 4; ++r) {
        int node = (qb + qs) * 16 + j * 4 + r;
        out[(size_t)bs * 262144 + (size_t)node * 512 + h * 64 + d] = o[qs][ds][r] * inv4[r];
      }
    }
  }
}

// ---- launcher ----
extern "C" void kernel_launch(void* const* d_in, const int* in_sizes, int n_in,
                              void* d_out, int out_size, void* d_ws, size_t ws_size,
                              hipStream_t stream) {
  const float* x  = (const float*)d_in[0];
  const int*   e  = (const int*)d_in[1];
  const float* Wq = (const float*)d_in[2];
  const float* bq = (const float*)d_in[3];
  const float* Wk = (const float*)d_in[4];
  const float* bk = (const float*)d_in[5];
  const float* Wv = (const float*)d_in[6];
  const float* bv = (const float*)d_in[7];
  float* out = (float*)d_out;

  char* ws = (char*)d_ws;
  u16* xb   = (u16*)(ws);                 // 24576*512 bf16 = 25165824 B
  u16* wb   = (u16*)(ws + 25165824);      // 3*512*512 bf16 = 1572864 B
  u16* qkv  = (u16*)(ws + 26738688);      // 3*384*512*64 bf16 = 75497472 B
  u32* mfr  = (u32*)(ws + 102236160);     // 131072 u32 = 524288 B

  hipMemsetAsync(mfr, 0, 524288, stream);
  edge_mf<<<(NEDGES + 255) / 256, 256, 0, stream>>>(e, mfr);

  cast_all<<<2048, 256, 0, stream>>>(x, Wq, Wk, Wv, xb, wb);

  qkv_gemm<<<2304, 256, 0, stream>>>(xb, wb, bq, bk, bv, qkv);
  attn_kernel<<<1536, 256, 0, stream>>>(qkv, mfr, out);
}